// Round 2
// baseline (1030.771 us; speedup 1.0000x reference)
//
#include <hip/hip_runtime.h>
#include <hip/hip_bf16.h>
#include <math.h>

// ContextAttention: B=128, S=2048, D=512, H=512
// hidden[b,h] = sum_s softmax_s(mask ? -inf : V . tanh(q[b]+ctx[b,:,s]))[s] * ctx[b,h,s]
// Key identity: hidden = W_ctx @ (sum_s score_s * contexts[b,s,:]) + b_ctx  (since sum score = 1)

#define B_N 128
#define S_N 2048
#define D_N 512
#define H_N 512

typedef __attribute__((ext_vector_type(8))) short bf16x8;
typedef __attribute__((ext_vector_type(4))) float f32x4;

__device__ __forceinline__ unsigned short f2bf(float x) {
  union { float f; unsigned int u; } v; v.f = x;
  unsigned int r = v.u + 0x7fffu + ((v.u >> 16) & 1u);  // RNE
  return (unsigned short)(r >> 16);
}

__device__ __forceinline__ float tanh_fast(float x) {
  float ax = fabsf(x);
  float e = __expf(2.0f * ax);          // overflow -> inf -> t = 1, correct
  float t = 1.0f - 2.0f / (e + 1.0f);
  return copysignf(t, x);
}

// ---------------- K-1: detect mask dtype (int32 0/1 vs 1-byte bool) -----------
// If mask is int32 0/1, the first 256 uint32 words are all <=1. If it's packed
// 0/1 bytes, P(all 256 words <= 1) = (1/8)^256 ~ 0. flag: 1=int32, 0=bytes.
__global__ void detect_mask_kernel(const unsigned int* __restrict__ mask,
                                   int* __restrict__ flag) {
  int tid = threadIdx.x;                 // 64 threads, 1 wave
  unsigned int bad = 0;
  for (int i = tid; i < 256; i += 64) bad |= (mask[i] > 1u) ? 1u : 0u;
  unsigned long long b = __ballot(bad != 0);
  if (tid == 0) *flag = (b == 0ull) ? 1 : 0;
}

// ---------------- K0: pack W_ctx -> bf16, pre-swizzled per-K-step LDS image ----
// tile t (k-range [t*64,t*64+64)) occupies 65536 B; inside: byte = h*128 + ((kk*2) ^ ((h&7)<<4))
__global__ __launch_bounds__(256) void packw_kernel(const float* __restrict__ Wc,
                                                    unsigned short* __restrict__ wpack) {
  int idx = blockIdx.x * 256 + threadIdx.x;   // 0..262143 == h*512 + kglob
  int h = idx >> 9;
  int kg = idx & 511;
  int t = kg >> 6, kk = kg & 63;
  int byte = t * 65536 + h * 128 + ((kk * 2) ^ ((h & 7) << 4));
  *(unsigned short*)((char*)wpack + byte) = f2bf(Wc[idx]);
}

// ---------------- K1: qpb[b,h] = inputs[b]·W_in[h] + b_in[h] + b_ctx[h] -------
__global__ __launch_bounds__(256) void qproj_kernel(const float* __restrict__ inp,
    const float* __restrict__ Win, const float* __restrict__ bin,
    const float* __restrict__ bctx, float* __restrict__ qpb) {
  int b = blockIdx.x, tid = threadIdx.x;
  __shared__ float xin[D_N];
  xin[tid] = inp[b * D_N + tid];
  xin[tid + 256] = inp[b * D_N + tid + 256];
  __syncthreads();
  #pragma unroll
  for (int hh = 0; hh < 2; ++hh) {
    int h = tid + hh * 256;
    const float4* wrow = (const float4*)(Win + (size_t)h * D_N);
    float s = 0.f;
    #pragma unroll 4
    for (int i = 0; i < 128; ++i) {
      float4 w = wrow[i];
      s += w.x * xin[i*4] + w.y * xin[i*4+1] + w.z * xin[i*4+2] + w.w * xin[i*4+3];
    }
    qpb[b * H_N + h] = s + bin[h] + bctx[h];
  }
}

// ---------------- K2: fused ctx-GEMM + tanh + V-reduce -> att (pre-softmax) ----
// Block: (b, s-tile of 128). C-tile = [128 s][512 h] bf16 MFMA; epilogue reduces over h.
__global__ __launch_bounds__(512, 2) void att_kernel(
    const float* __restrict__ ctxs, const void* __restrict__ mask,
    const int* __restrict__ mflag,
    const unsigned short* __restrict__ wpack, const float* __restrict__ qpb,
    const float* __restrict__ Vp, float* __restrict__ att_out) {
  __shared__ char lds[16384 + 65536];        // sA 16KB + sB 64KB = 80KB -> 2 blocks/CU
  char* sA = lds;
  char* sB = lds + 16384;
  float* att_red = (float*)lds;              // reused after final barrier (2KB)

  const int tid  = threadIdx.x;
  const int wid  = tid >> 6;
  const int lane = tid & 63;
  const int ln15 = lane & 15;
  const int lk   = lane >> 4;
  const int wr   = wid >> 2;   // 0..1 : s-half
  const int wc   = wid & 3;    // 0..3 : h-quarter (128 cols)

  const int bx = blockIdx.x;
  const int b  = bx >> 4;
  const int s0 = (bx & 15) * 128;

  f32x4 acc[4][8];
  #pragma unroll
  for (int mi = 0; mi < 4; ++mi)
    #pragma unroll
    for (int ni = 0; ni < 8; ++ni)
      acc[mi][ni] = (f32x4){0.f, 0.f, 0.f, 0.f};

  const float* actx = ctxs + ((size_t)b * S_N + s0) * D_N;

  for (int t = 0; t < 8; ++t) {
    const int k0 = t * 64;
    __syncthreads();
    // stage A: contexts[b, s0..s0+127, k0..k0+63] fp32 -> bf16, XOR-swizzled
    #pragma unroll
    for (int i = 0; i < 4; ++i) {
      int p = i * 512 + tid;           // flat float4 index, coalesced
      int r = p >> 4;                  // row 0..127
      int c = (p & 15) * 4;            // col 0..60
      float4 v = *(const float4*)(actx + (size_t)r * D_N + k0 + c);
      unsigned int lo = (unsigned)f2bf(v.x) | ((unsigned)f2bf(v.y) << 16);
      unsigned int hi = (unsigned)f2bf(v.z) | ((unsigned)f2bf(v.w) << 16);
      int byte = r * 128 + ((c * 2) ^ ((r & 7) << 4));
      *(uint2*)(sA + byte) = make_uint2(lo, hi);
    }
    // stage B: 64KB of pre-swizzled W tile via async global->LDS, width 16
    {
      const char* wsrc = (const char*)wpack + t * 65536;
      #pragma unroll
      for (int i = 0; i < 8; ++i) {
        int ci = wid * 8 + i;          // 1KB chunk per wave-issue
        const char* g = wsrc + ci * 1024 + lane * 16;
        char* l = sB + ci * 1024 + lane * 16;
        __builtin_amdgcn_global_load_lds(
            (const __attribute__((address_space(1))) unsigned int*)g,
            (__attribute__((address_space(3))) unsigned int*)l, 16, 0, 0);
      }
    }
    __syncthreads();
    // compute: 2 kk-steps x 4 mi x 8 ni MFMA 16x16x32
    #pragma unroll
    for (int kk = 0; kk < 64; kk += 32) {
      const int kb2 = (kk + lk * 8) * 2;
      bf16x8 af[4];
      #pragma unroll
      for (int mi = 0; mi < 4; ++mi) {
        int r = wr * 64 + mi * 16 + ln15;
        af[mi] = *(const bf16x8*)(sA + r * 128 + (kb2 ^ ((r & 7) << 4)));
      }
      #pragma unroll
      for (int ni = 0; ni < 8; ++ni) {
        int h = wc * 128 + ni * 16 + ln15;
        bf16x8 bfr = *(const bf16x8*)(sB + h * 128 + (kb2 ^ ((h & 7) << 4)));
        #pragma unroll
        for (int mi = 0; mi < 4; ++mi)
          acc[mi][ni] = __builtin_amdgcn_mfma_f32_16x16x32_bf16(af[mi], bfr, acc[mi][ni], 0, 0, 0);
      }
    }
  }

  // epilogue: att[s] = sum_h V[h] * tanh(qpb[b,h] + ctx[h][s])
  float qv[8], vv[8];
  #pragma unroll
  for (int ni = 0; ni < 8; ++ni) {
    int h = wc * 128 + ni * 16 + ln15;
    qv[ni] = qpb[b * H_N + h];
    vv[ni] = Vp[h];
  }
  float part[4][4];
  #pragma unroll
  for (int mi = 0; mi < 4; ++mi)
    #pragma unroll
    for (int j = 0; j < 4; ++j) {
      float s = 0.f;
      #pragma unroll
      for (int ni = 0; ni < 8; ++ni)
        s += vv[ni] * tanh_fast(qv[ni] + acc[mi][ni][j]);
      part[mi][j] = s;
    }
  // reduce over the 16 lanes holding different h within each k-group
  #pragma unroll
  for (int mi = 0; mi < 4; ++mi)
    #pragma unroll
    for (int j = 0; j < 4; ++j) {
      float p = part[mi][j];
      p += __shfl_xor(p, 1, 64);
      p += __shfl_xor(p, 2, 64);
      p += __shfl_xor(p, 4, 64);
      p += __shfl_xor(p, 8, 64);
      part[mi][j] = p;
    }
  __syncthreads();                 // all sA reads done -> safe to reuse as att_red
  if (ln15 == 0) {
    #pragma unroll
    for (int mi = 0; mi < 4; ++mi)
      #pragma unroll
      for (int j = 0; j < 4; ++j)
        att_red[wid * 64 + mi * 16 + lk * 4 + j] = part[mi][j];
  }
  __syncthreads();
  if (tid < 128) {
    int s = tid;
    int wrr = s >> 6, sl = s & 63;
    float a = att_red[(wrr * 4 + 0) * 64 + sl] + att_red[(wrr * 4 + 1) * 64 + sl]
            + att_red[(wrr * 4 + 2) * 64 + sl] + att_red[(wrr * 4 + 3) * 64 + sl];
    size_t idx = (size_t)b * S_N + s0 + s;
    int mk = (*mflag) ? ((const int*)mask)[idx]
                      : (int)((const unsigned char*)mask)[idx];
    att_out[idx] = mk ? -INFINITY : a;
  }
}

// ---------------- K3: masked softmax over S, in place in the score output -----
__global__ __launch_bounds__(256) void softmax_kernel(float* __restrict__ score) {
  int b = blockIdx.x, tid = threadIdx.x;
  float* row = score + (size_t)b * S_N;
  float v[8];
  float m = -INFINITY;
  #pragma unroll
  for (int i = 0; i < 8; ++i) { v[i] = row[tid + i * 256]; m = fmaxf(m, v[i]); }
  #pragma unroll
  for (int d = 1; d < 64; d <<= 1) m = fmaxf(m, __shfl_xor(m, d, 64));
  __shared__ float redm[4], reds[4];
  int w = tid >> 6;
  if ((tid & 63) == 0) redm[w] = m;
  __syncthreads();
  m = fmaxf(fmaxf(redm[0], redm[1]), fmaxf(redm[2], redm[3]));
  float ssum = 0.f;
  #pragma unroll
  for (int i = 0; i < 8; ++i) { float e = __expf(v[i] - m); v[i] = e; ssum += e; }
  #pragma unroll
  for (int d = 1; d < 64; d <<= 1) ssum += __shfl_xor(ssum, d, 64);
  if ((tid & 63) == 0) reds[w] = ssum;
  __syncthreads();
  float inv = 1.0f / (reds[0] + reds[1] + reds[2] + reds[3]);
  #pragma unroll
  for (int i = 0; i < 8; ++i) row[tid + i * 256] = v[i] * inv;
}

// ---------------- K4: cbar[b,d] = sum_s score[b,s] * contexts[b,s,d] ----------
__global__ __launch_bounds__(256) void cbar_kernel(const float* __restrict__ ctxs,
    const float* __restrict__ score, float* __restrict__ cbar) {
  int bx = blockIdx.x;
  int b = bx >> 3, ch = bx & 7;
  int tid = threadIdx.x;
  int d = tid * 2;
  float ax = 0.f, ay = 0.f;
  const float* base = ctxs + ((size_t)b * S_N + ch * 256) * D_N + d;
  const float* sc = score + (size_t)b * S_N + ch * 256;
  #pragma unroll 4
  for (int s = 0; s < 256; ++s) {
    float w = sc[s];
    float2 c = *(const float2*)(base + (size_t)s * D_N);
    ax += w * c.x; ay += w * c.y;
  }
  atomicAdd(&cbar[b * D_N + d], ax);
  atomicAdd(&cbar[b * D_N + d + 1], ay);
}

// ---------------- K5: hidden[b,h] = W_ctx[h]·cbar[b] + b_ctx[h] (exact fp32) --
__global__ __launch_bounds__(256) void hidden_kernel(const float* __restrict__ Wc,
    const float* __restrict__ bctx, const float* __restrict__ cbar,
    float* __restrict__ hid) {
  int b = blockIdx.x, tid = threadIdx.x;
  __shared__ float cb[D_N];
  cb[tid] = cbar[b * D_N + tid];
  cb[tid + 256] = cbar[b * D_N + tid + 256];
  __syncthreads();
  #pragma unroll
  for (int hh = 0; hh < 2; ++hh) {
    int h = tid + hh * 256;
    const float4* wrow = (const float4*)(Wc + (size_t)h * D_N);
    float s = 0.f;
    #pragma unroll 4
    for (int i = 0; i < 128; ++i) {
      float4 w = wrow[i];
      s += w.x * cb[i*4] + w.y * cb[i*4+1] + w.z * cb[i*4+2] + w.w * cb[i*4+3];
    }
    hid[b * H_N + h] = s + bctx[h];
  }
}

extern "C" void kernel_launch(void* const* d_in, const int* in_sizes, int n_in,
                              void* d_out, int out_size, void* d_ws, size_t ws_size,
                              hipStream_t stream) {
  const float* inputs = (const float*)d_in[0];
  const float* ctxs   = (const float*)d_in[1];
  const void*  mask   = d_in[2];               // bool in ref; dtype detected on-device
  const float* Win    = (const float*)d_in[3];
  const float* bin    = (const float*)d_in[4];
  const float* Wc     = (const float*)d_in[5];
  const float* bctx   = (const float*)d_in[6];
  const float* Vp     = (const float*)d_in[7];

  float* hidden = (float*)d_out;               // [B,H]
  float* score  = (float*)d_out + B_N * H_N;   // [B,S] (att staged here pre-softmax)

  char* ws = (char*)d_ws;
  unsigned short* wpack = (unsigned short*)ws;       // 512 KB swizzled bf16 W_ctx
  float* qpb  = (float*)(ws + 512 * 1024);           // 256 KB q + b_ctx
  float* cbar = (float*)(ws + 768 * 1024);           // 256 KB weighted context sum
  int*   mflag = (int*)(ws + 1024 * 1024);           // 4 B mask-dtype flag

  hipMemsetAsync(cbar, 0, B_N * D_N * sizeof(float), stream);
  detect_mask_kernel<<<1, 64, 0, stream>>>((const unsigned int*)mask, mflag);
  packw_kernel<<<H_N * D_N / 256, 256, 0, stream>>>(Wc, wpack);
  qproj_kernel<<<B_N, 256, 0, stream>>>(inputs, Win, bin, bctx, qpb);
  att_kernel<<<B_N * (S_N / 128), 512, 0, stream>>>(ctxs, mask, mflag, wpack, qpb, Vp, score);
  softmax_kernel<<<B_N, 256, 0, stream>>>(score);
  cbar_kernel<<<B_N * 8, 256, 0, stream>>>(ctxs, score, cbar);
  hidden_kernel<<<B_N, 256, 0, stream>>>(Wc, bctx, cbar, hidden);
}